// Round 1
// baseline (316.173 us; speedup 1.0000x reference)
//
#include <hip/hip_runtime.h>
#include <math.h>

#define B_ 4
#define L_ 2048
#define H_ 8
#define D_ 64
#define SK 40
#define NTOP 40
#define HD (H_*D_)

typedef float4 f4;

// readlane: broadcast lane `l`'s value of v (uniform l) -> SGPR
static __device__ __forceinline__ float rl(float v, int l) {
  return __int_as_float(__builtin_amdgcn_readlane(__float_as_int(v), l));
}

// ---------------- Phase 1: M[bh,q] = max_s(Q.K_s) - sum_s(Q.K_s)/L ----------
// 8-lane groups; one query per group; 8 queries per wave; 32 per block.
__global__ __launch_bounds__(256) void k_sampleM(
    const float* __restrict__ Q, const float* __restrict__ K,
    const int* __restrict__ samp, float* __restrict__ M)
{
  int w = threadIdx.x >> 6, lane = threadIdx.x & 63;
  int g = lane >> 3, li = lane & 7;
  int gq = (blockIdx.x * 4 + w) * 8 + g;        // bh*L + qpos
  int qpos = gq & (L_ - 1);
  int bh = gq >> 11;
  int h = bh & (H_ - 1), b = bh >> 3;
  const size_t bhoff = (size_t)b * L_ * HD + (size_t)h * D_;
  const f4* qrow = (const f4*)(Q + bhoff + (size_t)qpos * HD);
  f4 q0 = qrow[li], q1 = qrow[li + 8];          // contiguous 128B halves
  const int* srow = samp + qpos * SK;
  const float* kb = K + bhoff;
  float mx = -INFINITY, sm = 0.f;
  #pragma unroll 4
  for (int s = 0; s < SK; ++s) {
    int ki = srow[s];
    const f4* krow = (const f4*)(kb + (size_t)ki * HD);
    f4 k0 = krow[li], k1 = krow[li + 8];
    float p = q0.x*k0.x + q0.y*k0.y + q0.z*k0.z + q0.w*k0.w
            + q1.x*k1.x + q1.y*k1.y + q1.z*k1.z + q1.w*k1.w;
    p += __shfl_xor(p, 1);
    p += __shfl_xor(p, 2);
    p += __shfl_xor(p, 4);
    mx = fmaxf(mx, p);
    sm += p;
  }
  if (li == 0) M[gq] = mx - sm * (1.0f / L_);
}

// ---------------- Phase 2: top-40 per (b,h), tie -> lower index -------------
__global__ __launch_bounds__(64) void k_topk(
    const float* __restrict__ M, int* __restrict__ top)
{
  __shared__ float sv[L_];
  int bh = blockIdx.x;
  int lane = threadIdx.x;
  for (int i = lane; i < L_; i += 64) sv[i] = M[bh * L_ + i];
  // single wave: LDS write->read ordered by lgkmcnt, no barrier needed
  for (int r = 0; r < NTOP; ++r) {
    float bv = -INFINITY; int bi = 0x7fffffff;
    for (int i = lane; i < L_; i += 64) {
      float v = sv[i];
      if (v > bv) { bv = v; bi = i; }          // ascending i -> first max kept
    }
    #pragma unroll
    for (int off = 32; off; off >>= 1) {
      float ov = __shfl_xor(bv, off);
      int   oi = __shfl_xor(bi, off);
      if (ov > bv || (ov == bv && oi < bi)) { bv = ov; bi = oi; }
    }
    if (lane == 0) top[bh * NTOP + r] = bi;
    sv[bi] = -INFINITY;                        // all lanes same addr: benign
  }
}

// ---------------- Phase 3: Vmean[bh,d] ---------------------------------------
__global__ __launch_bounds__(256) void k_vmean(
    const float* __restrict__ V, float* __restrict__ vm)
{
  __shared__ float part[4][64];
  int bh = blockIdx.x; int h = bh & 7, b = bh >> 3;
  int w = threadIdx.x >> 6, lane = threadIdx.x & 63;
  const float* vb = V + (size_t)b * L_ * HD + (size_t)h * D_ + lane;
  float s = 0.f;
  for (int l = w; l < L_; l += 4) s += vb[(size_t)l * HD];
  part[w][lane] = s;
  __syncthreads();
  if (threadIdx.x < 64) {
    float t = part[0][lane] + part[1][lane] + part[2][lane] + part[3][lane];
    vm[bh * 64 + lane] = t * (1.0f / L_);
  }
}

// ---------------- Phase 4a: fill out with Vmean broadcast --------------------
__global__ __launch_bounds__(256) void k_fill(
    const float* __restrict__ vm, float* __restrict__ out)
{
  int i = blockIdx.x * 256 + threadIdx.x;      // float4 index, 1M total
  int d4 = i & 15;
  int h  = (i >> 4) & 7;
  int b  = i >> 18;
  ((f4*)out)[i] = ((const f4*)vm)[(b * 8 + h) * 16 + d4];
}

// ---------------- Phase 4b: attention partials -------------------------------
// wave = (bh, ch of 64 keys, uq of 10 rows); lane = key for QK, lane = d for PV
__global__ __launch_bounds__(256) void k_attn(
    const float* __restrict__ Q, const float* __restrict__ K,
    const float* __restrict__ V, const int* __restrict__ top,
    float* __restrict__ pm, float* __restrict__ pl, float* __restrict__ pacc)
{
  int w = threadIdx.x >> 6, lane = threadIdx.x & 63;
  int gw = blockIdx.x * 4 + w;                 // ((bh*32+ch)*4 + uq)
  int uq = gw & 3;
  int ch = (gw >> 2) & 31;
  int bh = gw >> 7;
  int h = bh & 7, b = bh >> 3;
  const size_t bhoff = (size_t)b * L_ * HD + (size_t)h * D_;
  const int kbase = ch * 64;

  f4 kr[16];                                   // this lane's key row (64 f32)
  {
    const f4* krow = (const f4*)(K + bhoff + (size_t)(kbase + lane) * HD);
    #pragma unroll
    for (int j = 0; j < 16; ++j) kr[j] = krow[j];
  }
  float qlv[10];                               // lane d holds Q[u][d]
  #pragma unroll
  for (int u = 0; u < 10; ++u) {
    int pos = top[bh * NTOP + uq * 10 + u];
    qlv[u] = Q[bhoff + (size_t)pos * HD + lane];
  }
  float s[10];
  #pragma unroll
  for (int u = 0; u < 10; ++u) s[u] = 0.f;
  #pragma unroll
  for (int j = 0; j < 16; ++j) {
    f4 kv = kr[j];
    #pragma unroll
    for (int u = 0; u < 10; ++u) {
      s[u] = fmaf(rl(qlv[u], 4*j+0), kv.x, s[u]);
      s[u] = fmaf(rl(qlv[u], 4*j+1), kv.y, s[u]);
      s[u] = fmaf(rl(qlv[u], 4*j+2), kv.z, s[u]);
      s[u] = fmaf(rl(qlv[u], 4*j+3), kv.w, s[u]);
    }
  }
  float p[10];
  #pragma unroll
  for (int u = 0; u < 10; ++u) {
    float sv = s[u] * 0.125f;                  // 1/sqrt(64)
    float mx = sv;
    #pragma unroll
    for (int off = 32; off; off >>= 1) mx = fmaxf(mx, __shfl_xor(mx, off));
    float pv = __expf(sv - mx);
    float ls = pv;
    #pragma unroll
    for (int off = 32; off; off >>= 1) ls += __shfl_xor(ls, off);
    p[u] = pv;
    int e = (bh * 32 + ch) * NTOP + uq * 10 + u;
    if (lane == 0) { pm[e] = mx; pl[e] = ls; }
  }
  float acc[10];
  #pragma unroll
  for (int u = 0; u < 10; ++u) acc[u] = 0.f;
  const float* vb = V + bhoff + (size_t)kbase * HD + lane;
  #pragma unroll 4
  for (int k = 0; k < 64; ++k) {
    float vv = vb[(size_t)k * HD];             // coalesced: lane = d
    #pragma unroll
    for (int u = 0; u < 10; ++u)
      acc[u] = fmaf(rl(p[u], k), vv, acc[u]);  // k uniform -> readlane w/ SGPR
  }
  #pragma unroll
  for (int u = 0; u < 10; ++u) {
    size_t e = (size_t)(bh * 32 + ch) * NTOP + uq * 10 + u;
    pacc[e * 64 + lane] = acc[u];
  }
}

// ---------------- Phase 5: merge partials + scatter --------------------------
__global__ __launch_bounds__(256) void k_merge(
    const float* __restrict__ pm, const float* __restrict__ pl,
    const float* __restrict__ pacc, const int* __restrict__ top,
    float* __restrict__ out)
{
  int w = threadIdx.x >> 6, lane = threadIdx.x & 63;
  int gw = blockIdx.x * 4 + w;                 // bh*40 + u, 1280 total
  int bh = gw / NTOP, u = gw - bh * NTOP;
  int h = bh & 7, b = bh >> 3;
  float M = -INFINITY, Ls = 0.f, o = 0.f;
  for (int c = 0; c < 32; ++c) {
    int e = (bh * 32 + c) * NTOP + u;
    float mc = pm[e], lc = pl[e];
    float a = pacc[(size_t)e * 64 + lane];
    float Mn = fmaxf(M, mc);
    float f1 = __expf(M - Mn), f2 = __expf(mc - Mn);
    o  = o  * f1 + a  * f2;
    Ls = Ls * f1 + lc * f2;
    M = Mn;
  }
  int pos = top[bh * NTOP + u];
  out[((size_t)(b * L_ + pos) * H_ + h) * D_ + lane] = o / Ls;
}

extern "C" void kernel_launch(void* const* d_in, const int* in_sizes, int n_in,
                              void* d_out, int out_size, void* d_ws, size_t ws_size,
                              hipStream_t stream) {
  const float* Q = (const float*)d_in[0];
  const float* K = (const float*)d_in[1];
  const float* V = (const float*)d_in[2];
  const int* samp = (const int*)d_in[3];
  float* out = (float*)d_out;

  float* ws    = (float*)d_ws;
  float* M     = ws;                       // 65536
  float* vmean = M + 65536;                // 2048
  float* pm    = vmean + 2048;             // 40960
  float* pl    = pm + 40960;               // 40960
  float* pacc  = pl + 40960;               // 2621440
  int*   top   = (int*)(pacc + 2621440);   // 1280 ints  (total ~11.1 MB)

  hipLaunchKernelGGL(k_sampleM, dim3(2048), dim3(256), 0, stream, Q, K, samp, M);
  hipLaunchKernelGGL(k_topk,   dim3(32),   dim3(64),  0, stream, M, top);
  hipLaunchKernelGGL(k_vmean,  dim3(32),   dim3(256), 0, stream, V, vmean);
  hipLaunchKernelGGL(k_fill,   dim3(4096), dim3(256), 0, stream, vmean, out);
  hipLaunchKernelGGL(k_attn,   dim3(1024), dim3(256), 0, stream, Q, K, V, top, pm, pl, pacc);
  hipLaunchKernelGGL(k_merge,  dim3(320),  dim3(256), 0, stream, pm, pl, pacc, top, out);
}

// Round 2
// 200.435 us; speedup vs baseline: 1.5774x; 1.5774x over previous
//
#include <hip/hip_runtime.h>
#include <math.h>

#define B_ 4
#define L_ 2048
#define H_ 8
#define D_ 64
#define SK 40
#define NTOP 40
#define HD (H_*D_)

typedef float4 f4;

// readlane: broadcast lane `l`'s value of v (uniform l) -> SGPR
static __device__ __forceinline__ float rl(float v, int l) {
  return __int_as_float(__builtin_amdgcn_readlane(__float_as_int(v), l));
}

// ---------------- Phase 1: M[bh,q] = max_s(Q.K_s) - sum_s(Q.K_s)/L ----------
// 8-lane groups; one query per group; 8 queries per wave; 32 per block.
__global__ __launch_bounds__(256) void k_sampleM(
    const float* __restrict__ Q, const float* __restrict__ K,
    const int* __restrict__ samp, float* __restrict__ M)
{
  int w = threadIdx.x >> 6, lane = threadIdx.x & 63;
  int g = lane >> 3, li = lane & 7;
  int gq = (blockIdx.x * 4 + w) * 8 + g;        // bh*L + qpos
  int qpos = gq & (L_ - 1);
  int bh = gq >> 11;
  int h = bh & (H_ - 1), b = bh >> 3;
  const size_t bhoff = (size_t)b * L_ * HD + (size_t)h * D_;
  const f4* qrow = (const f4*)(Q + bhoff + (size_t)qpos * HD);
  f4 q0 = qrow[li], q1 = qrow[li + 8];          // contiguous 128B halves
  const int* srow = samp + qpos * SK;
  const float* kb = K + bhoff;
  float mx = -INFINITY, sm = 0.f;
  #pragma unroll 4
  for (int s = 0; s < SK; ++s) {
    int ki = srow[s];
    const f4* krow = (const f4*)(kb + (size_t)ki * HD);
    f4 k0 = krow[li], k1 = krow[li + 8];
    float p = q0.x*k0.x + q0.y*k0.y + q0.z*k0.z + q0.w*k0.w
            + q1.x*k1.x + q1.y*k1.y + q1.z*k1.z + q1.w*k1.w;
    p += __shfl_xor(p, 1);
    p += __shfl_xor(p, 2);
    p += __shfl_xor(p, 4);
    mx = fmaxf(mx, p);
    sm += p;
  }
  if (li == 0) M[gq] = mx - sm * (1.0f / L_);
}

// ---------------- Phase 2: top-40 per (b,h), tie -> lower index -------------
__global__ __launch_bounds__(64) void k_topk(
    const float* __restrict__ M, int* __restrict__ top)
{
  __shared__ float sv[L_];
  int bh = blockIdx.x;
  int lane = threadIdx.x;
  for (int i = lane; i < L_; i += 64) sv[i] = M[bh * L_ + i];
  // single wave: LDS write->read ordered by lgkmcnt, no barrier needed
  for (int r = 0; r < NTOP; ++r) {
    float bv = -INFINITY; int bi = 0x7fffffff;
    for (int i = lane; i < L_; i += 64) {
      float v = sv[i];
      if (v > bv) { bv = v; bi = i; }          // ascending i -> first max kept
    }
    #pragma unroll
    for (int off = 32; off; off >>= 1) {
      float ov = __shfl_xor(bv, off);
      int   oi = __shfl_xor(bi, off);
      if (ov > bv || (ov == bv && oi < bi)) { bv = ov; bi = oi; }
    }
    if (lane == 0) top[bh * NTOP + r] = bi;
    sv[bi] = -INFINITY;                        // all lanes same addr: benign
  }
}

// ---------------- Phase 3a: partial V sums, 64 rows per block ---------------
// grid: bh*32 + chunk (1024 blocks). 16 threads cover one row (16 float4).
__global__ __launch_bounds__(256) void k_vmean1(
    const float* __restrict__ V, float* __restrict__ part)
{
  __shared__ f4 red[16][16];
  int bh = blockIdx.x >> 5, chunk = blockIdx.x & 31;
  int h = bh & 7, b = bh >> 3;
  int t = threadIdx.x;
  int d4 = t & 15, rg = t >> 4;                // rg: 0..15 row-group
  const f4* vb = (const f4*)(V + (size_t)b * L_ * HD + (size_t)h * D_);
  f4 s = {0.f, 0.f, 0.f, 0.f};
  int row0 = chunk * 64 + rg;
  #pragma unroll
  for (int r = 0; r < 4; ++r) {
    f4 v = vb[(size_t)(row0 + r * 16) * (HD / 4) + d4];
    s.x += v.x; s.y += v.y; s.z += v.z; s.w += v.w;
  }
  red[rg][d4] = s;
  __syncthreads();
  #pragma unroll
  for (int off = 8; off; off >>= 1) {
    if (rg < off) {
      f4 a = red[rg][d4], bb = red[rg + off][d4];
      a.x += bb.x; a.y += bb.y; a.z += bb.z; a.w += bb.w;
      red[rg][d4] = a;
    }
    __syncthreads();
  }
  if (rg == 0) ((f4*)part)[(size_t)blockIdx.x * 16 + d4] = red[0][d4];
}

// ---------------- Phase 3b: reduce 32 chunk partials -> vmean ---------------
__global__ __launch_bounds__(64) void k_vmean2(
    const float* __restrict__ part, float* __restrict__ vm)
{
  int bh = blockIdx.x, lane = threadIdx.x;     // lane = d
  float s = 0.f;
  #pragma unroll 8
  for (int c = 0; c < 32; ++c)
    s += part[(size_t)(bh * 32 + c) * 64 + lane];
  vm[bh * 64 + lane] = s * (1.0f / L_);
}

// ---------------- Phase 4a: fill out with Vmean broadcast --------------------
__global__ __launch_bounds__(256) void k_fill(
    const float* __restrict__ vm, float* __restrict__ out)
{
  int i = blockIdx.x * 256 + threadIdx.x;      // float4 index, 1M total
  int d4 = i & 15;
  int h  = (i >> 4) & 7;
  int b  = i >> 18;
  ((f4*)out)[i] = ((const f4*)vm)[(b * 8 + h) * 16 + d4];
}

// ---------------- Phase 4b: attention partials -------------------------------
// wave = (bh, ch of 64 keys, uq of 10 rows); lane = key for QK, lane = d for PV
__global__ __launch_bounds__(256) void k_attn(
    const float* __restrict__ Q, const float* __restrict__ K,
    const float* __restrict__ V, const int* __restrict__ top,
    float* __restrict__ pm, float* __restrict__ pl, float* __restrict__ pacc)
{
  int w = threadIdx.x >> 6, lane = threadIdx.x & 63;
  int gw = blockIdx.x * 4 + w;                 // ((bh*32+ch)*4 + uq)
  int uq = gw & 3;
  int ch = (gw >> 2) & 31;
  int bh = gw >> 7;
  int h = bh & 7, b = bh >> 3;
  const size_t bhoff = (size_t)b * L_ * HD + (size_t)h * D_;
  const int kbase = ch * 64;

  f4 kr[16];                                   // this lane's key row (64 f32)
  {
    const f4* krow = (const f4*)(K + bhoff + (size_t)(kbase + lane) * HD);
    #pragma unroll
    for (int j = 0; j < 16; ++j) kr[j] = krow[j];
  }
  float qlv[10];                               // lane d holds Q[u][d]
  #pragma unroll
  for (int u = 0; u < 10; ++u) {
    int pos = top[bh * NTOP + uq * 10 + u];
    qlv[u] = Q[bhoff + (size_t)pos * HD + lane];
  }
  float s[10];
  #pragma unroll
  for (int u = 0; u < 10; ++u) s[u] = 0.f;
  #pragma unroll
  for (int j = 0; j < 16; ++j) {
    f4 kv = kr[j];
    #pragma unroll
    for (int u = 0; u < 10; ++u) {
      s[u] = fmaf(rl(qlv[u], 4*j+0), kv.x, s[u]);
      s[u] = fmaf(rl(qlv[u], 4*j+1), kv.y, s[u]);
      s[u] = fmaf(rl(qlv[u], 4*j+2), kv.z, s[u]);
      s[u] = fmaf(rl(qlv[u], 4*j+3), kv.w, s[u]);
    }
  }
  float p[10];
  #pragma unroll
  for (int u = 0; u < 10; ++u) {
    float sv = s[u] * 0.125f;                  // 1/sqrt(64)
    float mx = sv;
    #pragma unroll
    for (int off = 32; off; off >>= 1) mx = fmaxf(mx, __shfl_xor(mx, off));
    float pv = __expf(sv - mx);
    float ls = pv;
    #pragma unroll
    for (int off = 32; off; off >>= 1) ls += __shfl_xor(ls, off);
    p[u] = pv;
    int e = (bh * 32 + ch) * NTOP + uq * 10 + u;
    if (lane == 0) { pm[e] = mx; pl[e] = ls; }
  }
  float acc[10];
  #pragma unroll
  for (int u = 0; u < 10; ++u) acc[u] = 0.f;
  const float* vb = V + bhoff + (size_t)kbase * HD + lane;
  #pragma unroll 4
  for (int k = 0; k < 64; ++k) {
    float vv = vb[(size_t)k * HD];             // coalesced: lane = d
    #pragma unroll
    for (int u = 0; u < 10; ++u)
      acc[u] = fmaf(rl(p[u], k), vv, acc[u]);  // k uniform -> readlane w/ SGPR
  }
  #pragma unroll
  for (int u = 0; u < 10; ++u) {
    size_t e = (size_t)(bh * 32 + ch) * NTOP + uq * 10 + u;
    pacc[e * 64 + lane] = acc[u];
  }
}

// ---------------- Phase 5: merge partials + scatter --------------------------
__global__ __launch_bounds__(256) void k_merge(
    const float* __restrict__ pm, const float* __restrict__ pl,
    const float* __restrict__ pacc, const int* __restrict__ top,
    float* __restrict__ out)
{
  int w = threadIdx.x >> 6, lane = threadIdx.x & 63;
  int gw = blockIdx.x * 4 + w;                 // bh*40 + u, 1280 total
  int bh = gw / NTOP, u = gw - bh * NTOP;
  int h = bh & 7, b = bh >> 3;
  float M = -INFINITY, Ls = 0.f, o = 0.f;
  for (int c = 0; c < 32; ++c) {
    int e = (bh * 32 + c) * NTOP + u;
    float mc = pm[e], lc = pl[e];
    float a = pacc[(size_t)e * 64 + lane];
    float Mn = fmaxf(M, mc);
    float f1 = __expf(M - Mn), f2 = __expf(mc - Mn);
    o  = o  * f1 + a  * f2;
    Ls = Ls * f1 + lc * f2;
    M = Mn;
  }
  int pos = top[bh * NTOP + u];
  out[((size_t)(b * L_ + pos) * H_ + h) * D_ + lane] = o / Ls;
}

extern "C" void kernel_launch(void* const* d_in, const int* in_sizes, int n_in,
                              void* d_out, int out_size, void* d_ws, size_t ws_size,
                              hipStream_t stream) {
  const float* Q = (const float*)d_in[0];
  const float* K = (const float*)d_in[1];
  const float* V = (const float*)d_in[2];
  const int* samp = (const int*)d_in[3];
  float* out = (float*)d_out;

  float* ws    = (float*)d_ws;
  float* M     = ws;                       // 65536
  float* vmean = M + 65536;                // 2048
  float* pm    = vmean + 2048;             // 40960
  float* pl    = pm + 40960;               // 40960
  float* pacc  = pl + 40960;               // 2621440
  int*   top   = (int*)(pacc + 2621440);   // 1280 ints  (total ~11.1 MB)
  float* vpart = pacc;                     // alias: used only BEFORE k_attn

  hipLaunchKernelGGL(k_sampleM, dim3(2048), dim3(256), 0, stream, Q, K, samp, M);
  hipLaunchKernelGGL(k_topk,   dim3(32),   dim3(64),  0, stream, M, top);
  hipLaunchKernelGGL(k_vmean1, dim3(1024), dim3(256), 0, stream, V, vpart);
  hipLaunchKernelGGL(k_vmean2, dim3(32),   dim3(64),  0, stream, vpart, vmean);
  hipLaunchKernelGGL(k_fill,   dim3(4096), dim3(256), 0, stream, vmean, out);
  hipLaunchKernelGGL(k_attn,   dim3(1024), dim3(256), 0, stream, Q, K, V, top, pm, pl, pacc);
  hipLaunchKernelGGL(k_merge,  dim3(320),  dim3(256), 0, stream, pm, pl, pacc, top, out);
}

// Round 3
// 151.449 us; speedup vs baseline: 2.0877x; 1.3235x over previous
//
#include <hip/hip_runtime.h>
#include <math.h>

#define B_ 4
#define L_ 2048
#define H_ 8
#define D_ 64
#define SK 40
#define NTOP 40
#define HD (H_*D_)

typedef float4 f4;

// readlane: broadcast lane `l`'s value of v (uniform l) -> SGPR
static __device__ __forceinline__ float rl(float v, int l) {
  return __int_as_float(__builtin_amdgcn_readlane(__float_as_int(v), l));
}

// ---------------- Phase 1: M[bh,q] = max_s(Q.K_s) - sum_s(Q.K_s)/L ----------
// 8-lane groups; one query per group; 8 queries per wave; 32 per block.
__global__ __launch_bounds__(256) void k_sampleM(
    const float* __restrict__ Q, const float* __restrict__ K,
    const int* __restrict__ samp, float* __restrict__ M)
{
  int w = threadIdx.x >> 6, lane = threadIdx.x & 63;
  int g = lane >> 3, li = lane & 7;
  int gq = (blockIdx.x * 4 + w) * 8 + g;        // bh*L + qpos
  int qpos = gq & (L_ - 1);
  int bh = gq >> 11;
  int h = bh & (H_ - 1), b = bh >> 3;
  const size_t bhoff = (size_t)b * L_ * HD + (size_t)h * D_;
  const f4* qrow = (const f4*)(Q + bhoff + (size_t)qpos * HD);
  f4 q0 = qrow[li], q1 = qrow[li + 8];          // contiguous 128B halves
  const int* srow = samp + qpos * SK;
  const float* kb = K + bhoff;
  float mx = -INFINITY, sm = 0.f;
  #pragma unroll 4
  for (int s = 0; s < SK; ++s) {
    int ki = srow[s];
    const f4* krow = (const f4*)(kb + (size_t)ki * HD);
    f4 k0 = krow[li], k1 = krow[li + 8];
    float p = q0.x*k0.x + q0.y*k0.y + q0.z*k0.z + q0.w*k0.w
            + q1.x*k1.x + q1.y*k1.y + q1.z*k1.z + q1.w*k1.w;
    p += __shfl_xor(p, 1);
    p += __shfl_xor(p, 2);
    p += __shfl_xor(p, 4);
    mx = fmaxf(mx, p);
    sm += p;
  }
  if (li == 0) M[gq] = mx - sm * (1.0f / L_);
}

// ---------------- Phase 2: top-40 per (b,h) via 4-pass radix select ----------
// One 256-thread block per bh. Set semantics: order in top[] is irrelevant;
// ties at the boundary take lowest indices (matches lax.top_k).
__global__ __launch_bounds__(256) void k_topk(
    const float* __restrict__ M, int* __restrict__ top)
{
  __shared__ unsigned hist[256];
  __shared__ int s_sel, s_k;
  __shared__ unsigned s_ngt, s_neq;
  __shared__ int eqidx[L_];
  int bh = blockIdx.x, t = threadIdx.x;

  unsigned v[8];                               // monotone float->uint map
  #pragma unroll
  for (int j = 0; j < 8; ++j) {
    unsigned u = __float_as_uint(M[bh * L_ + t + j * 256]);
    v[j] = (u & 0x80000000u) ? ~u : (u | 0x80000000u);
  }

  unsigned prefix = 0;
  int kneed = NTOP;
  for (int shift = 24; shift >= 0; shift -= 8) {
    hist[t] = 0;
    __syncthreads();
    unsigned msk = (shift == 24) ? 0u : (0xFFFFFFFFu << (shift + 8));
    #pragma unroll
    for (int j = 0; j < 8; ++j)
      if ((v[j] & msk) == prefix)
        atomicAdd(&hist[(v[j] >> shift) & 255u], 1u);
    __syncthreads();
    if (t == 0) {
      int kk = kneed, b = 0;
      for (b = 255; b > 0; --b) {
        int c = (int)hist[b];
        if (c >= kk) break;
        kk -= c;
      }
      s_sel = b; s_k = kk;
    }
    __syncthreads();
    prefix |= ((unsigned)s_sel) << shift;
    kneed = s_k;
  }
  // prefix == exact bit pattern of the 40th-largest value (tie-counted);
  // kneed == how many values equal to it we must take (lowest indices).
  if (t == 0) { s_ngt = 0; s_neq = 0; }
  __syncthreads();
  #pragma unroll
  for (int j = 0; j < 8; ++j) {
    if (v[j] > prefix) {
      unsigned p = atomicAdd(&s_ngt, 1u);
      top[bh * NTOP + p] = t + j * 256;
    } else if (v[j] == prefix) {
      unsigned p = atomicAdd(&s_neq, 1u);
      eqidx[p] = t + j * 256;
    }
  }
  __syncthreads();
  if (t == 0) {
    int base = NTOP - kneed;                   // == s_ngt
    int n = (int)s_neq;
    for (int r = 0; r < kneed; ++r) {
      int bm = 0x7fffffff, bp = 0;
      for (int i = 0; i < n; ++i)
        if (eqidx[i] < bm) { bm = eqidx[i]; bp = i; }
      top[bh * NTOP + base + r] = bm;
      eqidx[bp] = 0x7fffffff;
    }
  }
}

// ---------------- Phase 3a: partial V sums, 64 rows per block ---------------
// grid: bh*32 + chunk (1024 blocks). 16 threads cover one row (16 float4).
__global__ __launch_bounds__(256) void k_vmean1(
    const float* __restrict__ V, float* __restrict__ part)
{
  __shared__ f4 red[16][16];
  int bh = blockIdx.x >> 5, chunk = blockIdx.x & 31;
  int h = bh & 7, b = bh >> 3;
  int t = threadIdx.x;
  int d4 = t & 15, rg = t >> 4;                // rg: 0..15 row-group
  const f4* vb = (const f4*)(V + (size_t)b * L_ * HD + (size_t)h * D_);
  f4 s = {0.f, 0.f, 0.f, 0.f};
  int row0 = chunk * 64 + rg;
  #pragma unroll
  for (int r = 0; r < 4; ++r) {
    f4 v = vb[(size_t)(row0 + r * 16) * (HD / 4) + d4];
    s.x += v.x; s.y += v.y; s.z += v.z; s.w += v.w;
  }
  red[rg][d4] = s;
  __syncthreads();
  #pragma unroll
  for (int off = 8; off; off >>= 1) {
    if (rg < off) {
      f4 a = red[rg][d4], bb = red[rg + off][d4];
      a.x += bb.x; a.y += bb.y; a.z += bb.z; a.w += bb.w;
      red[rg][d4] = a;
    }
    __syncthreads();
  }
  if (rg == 0) ((f4*)part)[(size_t)blockIdx.x * 16 + d4] = red[0][d4];
}

// ---------------- Phase 3b: reduce 32 chunk partials -> vmean ---------------
__global__ __launch_bounds__(64) void k_vmean2(
    const float* __restrict__ part, float* __restrict__ vm)
{
  int bh = blockIdx.x, lane = threadIdx.x;     // lane = d
  float s = 0.f;
  #pragma unroll 8
  for (int c = 0; c < 32; ++c)
    s += part[(size_t)(bh * 32 + c) * 64 + lane];
  vm[bh * 64 + lane] = s * (1.0f / L_);
}

// ---------------- Phase 4a: fill out with Vmean broadcast --------------------
__global__ __launch_bounds__(256) void k_fill(
    const float* __restrict__ vm, float* __restrict__ out)
{
  int i = blockIdx.x * 256 + threadIdx.x;      // float4 index, 1M total
  int d4 = i & 15;
  int h  = (i >> 4) & 7;
  int b  = i >> 18;
  ((f4*)out)[i] = ((const f4*)vm)[(b * 8 + h) * 16 + d4];
}

// ---------------- Phase 4b: attention partials -------------------------------
// wave = (bh, ch of 64 keys, uq of 10 rows); lane = key for QK, lane = d for PV
__global__ __launch_bounds__(256) void k_attn(
    const float* __restrict__ Q, const float* __restrict__ K,
    const float* __restrict__ V, const int* __restrict__ top,
    float* __restrict__ pm, float* __restrict__ pl, float* __restrict__ pacc)
{
  int w = threadIdx.x >> 6, lane = threadIdx.x & 63;
  int gw = blockIdx.x * 4 + w;                 // ((bh*32+ch)*4 + uq)
  int uq = gw & 3;
  int ch = (gw >> 2) & 31;
  int bh = gw >> 7;
  int h = bh & 7, b = bh >> 3;
  const size_t bhoff = (size_t)b * L_ * HD + (size_t)h * D_;
  const int kbase = ch * 64;

  f4 kr[16];                                   // this lane's key row (64 f32)
  {
    const f4* krow = (const f4*)(K + bhoff + (size_t)(kbase + lane) * HD);
    #pragma unroll
    for (int j = 0; j < 16; ++j) kr[j] = krow[j];
  }
  float qlv[10];                               // lane d holds Q[u][d]
  #pragma unroll
  for (int u = 0; u < 10; ++u) {
    int pos = top[bh * NTOP + uq * 10 + u];
    qlv[u] = Q[bhoff + (size_t)pos * HD + lane];
  }
  float s[10];
  #pragma unroll
  for (int u = 0; u < 10; ++u) s[u] = 0.f;
  #pragma unroll
  for (int j = 0; j < 16; ++j) {
    f4 kv = kr[j];
    #pragma unroll
    for (int u = 0; u < 10; ++u) {
      s[u] = fmaf(rl(qlv[u], 4*j+0), kv.x, s[u]);
      s[u] = fmaf(rl(qlv[u], 4*j+1), kv.y, s[u]);
      s[u] = fmaf(rl(qlv[u], 4*j+2), kv.z, s[u]);
      s[u] = fmaf(rl(qlv[u], 4*j+3), kv.w, s[u]);
    }
  }
  float p[10];
  #pragma unroll
  for (int u = 0; u < 10; ++u) {
    float sv = s[u] * 0.125f;                  // 1/sqrt(64)
    float mx = sv;
    #pragma unroll
    for (int off = 32; off; off >>= 1) mx = fmaxf(mx, __shfl_xor(mx, off));
    float pv = __expf(sv - mx);
    float ls = pv;
    #pragma unroll
    for (int off = 32; off; off >>= 1) ls += __shfl_xor(ls, off);
    p[u] = pv;
    int e = (bh * 32 + ch) * NTOP + uq * 10 + u;
    if (lane == 0) { pm[e] = mx; pl[e] = ls; }
  }
  float acc[10];
  #pragma unroll
  for (int u = 0; u < 10; ++u) acc[u] = 0.f;
  const float* vb = V + bhoff + (size_t)kbase * HD + lane;
  #pragma unroll 4
  for (int k = 0; k < 64; ++k) {
    float vv = vb[(size_t)k * HD];             // coalesced: lane = d
    #pragma unroll
    for (int u = 0; u < 10; ++u)
      acc[u] = fmaf(rl(p[u], k), vv, acc[u]);  // k uniform -> readlane w/ SGPR
  }
  #pragma unroll
  for (int u = 0; u < 10; ++u) {
    size_t e = (size_t)(bh * 32 + ch) * NTOP + uq * 10 + u;
    pacc[e * 64 + lane] = acc[u];
  }
}

// ---------------- Phase 5: merge partials + scatter --------------------------
__global__ __launch_bounds__(256) void k_merge(
    const float* __restrict__ pm, const float* __restrict__ pl,
    const float* __restrict__ pacc, const int* __restrict__ top,
    float* __restrict__ out)
{
  int w = threadIdx.x >> 6, lane = threadIdx.x & 63;
  int gw = blockIdx.x * 4 + w;                 // bh*40 + u, 1280 total
  int bh = gw / NTOP, u = gw - bh * NTOP;
  int h = bh & 7, b = bh >> 3;
  float M = -INFINITY, Ls = 0.f, o = 0.f;
  for (int c = 0; c < 32; ++c) {
    int e = (bh * 32 + c) * NTOP + u;
    float mc = pm[e], lc = pl[e];
    float a = pacc[(size_t)e * 64 + lane];
    float Mn = fmaxf(M, mc);
    float f1 = __expf(M - Mn), f2 = __expf(mc - Mn);
    o  = o  * f1 + a  * f2;
    Ls = Ls * f1 + lc * f2;
    M = Mn;
  }
  int pos = top[bh * NTOP + u];
  out[((size_t)(b * L_ + pos) * H_ + h) * D_ + lane] = o / Ls;
}

extern "C" void kernel_launch(void* const* d_in, const int* in_sizes, int n_in,
                              void* d_out, int out_size, void* d_ws, size_t ws_size,
                              hipStream_t stream) {
  const float* Q = (const float*)d_in[0];
  const float* K = (const float*)d_in[1];
  const float* V = (const float*)d_in[2];
  const int* samp = (const int*)d_in[3];
  float* out = (float*)d_out;

  float* ws    = (float*)d_ws;
  float* M     = ws;                       // 65536
  float* vmean = M + 65536;                // 2048
  float* pm    = vmean + 2048;             // 40960
  float* pl    = pm + 40960;               // 40960
  float* pacc  = pl + 40960;               // 2621440
  int*   top   = (int*)(pacc + 2621440);   // 1280 ints  (total ~11.1 MB)
  float* vpart = pacc;                     // alias: used only BEFORE k_attn

  hipLaunchKernelGGL(k_sampleM, dim3(2048), dim3(256), 0, stream, Q, K, samp, M);
  hipLaunchKernelGGL(k_topk,   dim3(32),   dim3(256), 0, stream, M, top);
  hipLaunchKernelGGL(k_vmean1, dim3(1024), dim3(256), 0, stream, V, vpart);
  hipLaunchKernelGGL(k_vmean2, dim3(32),   dim3(64),  0, stream, vpart, vmean);
  hipLaunchKernelGGL(k_fill,   dim3(4096), dim3(256), 0, stream, vmean, out);
  hipLaunchKernelGGL(k_attn,   dim3(1024), dim3(256), 0, stream, Q, K, V, top, pm, pl, pacc);
  hipLaunchKernelGGL(k_merge,  dim3(320),  dim3(256), 0, stream, pm, pl, pacc, top, out);
}

// Round 4
// 141.770 us; speedup vs baseline: 2.2302x; 1.0683x over previous
//
#include <hip/hip_runtime.h>
#include <math.h>

#define B_ 4
#define L_ 2048
#define H_ 8
#define D_ 64
#define SK 40
#define NTOP 40
#define HD (H_*D_)

typedef float4 f4;

// readlane: broadcast lane `l`'s value of v (uniform l) -> SGPR
static __device__ __forceinline__ float rl(float v, int l) {
  return __int_as_float(__builtin_amdgcn_readlane(__float_as_int(v), l));
}

// ---------------- Phase 1: M[bh,q] = max_s(Q.K_s) - sum_s(Q.K_s)/L ----------
// 8-lane groups; one query per group; 8 queries per wave; 32 per block.
__global__ __launch_bounds__(256) void k_sampleM(
    const float* __restrict__ Q, const float* __restrict__ K,
    const int* __restrict__ samp, float* __restrict__ M)
{
  int w = threadIdx.x >> 6, lane = threadIdx.x & 63;
  int g = lane >> 3, li = lane & 7;
  int gq = (blockIdx.x * 4 + w) * 8 + g;        // bh*L + qpos
  int qpos = gq & (L_ - 1);
  int bh = gq >> 11;
  int h = bh & (H_ - 1), b = bh >> 3;
  const size_t bhoff = (size_t)b * L_ * HD + (size_t)h * D_;
  const f4* qrow = (const f4*)(Q + bhoff + (size_t)qpos * HD);
  f4 q0 = qrow[li], q1 = qrow[li + 8];          // contiguous 128B halves
  const int* srow = samp + qpos * SK;
  const float* kb = K + bhoff;
  float mx = -INFINITY, sm = 0.f;
  #pragma unroll 4
  for (int s = 0; s < SK; ++s) {
    int ki = srow[s];
    const f4* krow = (const f4*)(kb + (size_t)ki * HD);
    f4 k0 = krow[li], k1 = krow[li + 8];
    float p = q0.x*k0.x + q0.y*k0.y + q0.z*k0.z + q0.w*k0.w
            + q1.x*k1.x + q1.y*k1.y + q1.z*k1.z + q1.w*k1.w;
    p += __shfl_xor(p, 1);
    p += __shfl_xor(p, 2);
    p += __shfl_xor(p, 4);
    mx = fmaxf(mx, p);
    sm += p;
  }
  if (li == 0) M[gq] = mx - sm * (1.0f / L_);
}

// ---------------- Phase 2: top-40 per (b,h) via 4-pass radix select ----------
// One 256-thread block per bh. Set semantics: order in top[] is irrelevant;
// ties at the boundary take lowest indices (matches lax.top_k).
__global__ __launch_bounds__(256) void k_topk(
    const float* __restrict__ M, int* __restrict__ top)
{
  __shared__ unsigned hist[256];
  __shared__ int s_sel, s_k;
  __shared__ unsigned s_ngt, s_neq;
  __shared__ int eqidx[L_];
  int bh = blockIdx.x, t = threadIdx.x;

  unsigned v[8];                               // monotone float->uint map
  #pragma unroll
  for (int j = 0; j < 8; ++j) {
    unsigned u = __float_as_uint(M[bh * L_ + t + j * 256]);
    v[j] = (u & 0x80000000u) ? ~u : (u | 0x80000000u);
  }

  unsigned prefix = 0;
  int kneed = NTOP;
  for (int shift = 24; shift >= 0; shift -= 8) {
    hist[t] = 0;
    __syncthreads();
    unsigned msk = (shift == 24) ? 0u : (0xFFFFFFFFu << (shift + 8));
    #pragma unroll
    for (int j = 0; j < 8; ++j)
      if ((v[j] & msk) == prefix)
        atomicAdd(&hist[(v[j] >> shift) & 255u], 1u);
    __syncthreads();
    if (t == 0) {
      int kk = kneed, b = 0;
      for (b = 255; b > 0; --b) {
        int c = (int)hist[b];
        if (c >= kk) break;
        kk -= c;
      }
      s_sel = b; s_k = kk;
    }
    __syncthreads();
    prefix |= ((unsigned)s_sel) << shift;
    kneed = s_k;
  }
  // prefix == exact bit pattern of the 40th-largest value (tie-counted);
  // kneed == how many values equal to it we must take (lowest indices).
  if (t == 0) { s_ngt = 0; s_neq = 0; }
  __syncthreads();
  #pragma unroll
  for (int j = 0; j < 8; ++j) {
    if (v[j] > prefix) {
      unsigned p = atomicAdd(&s_ngt, 1u);
      top[bh * NTOP + p] = t + j * 256;
    } else if (v[j] == prefix) {
      unsigned p = atomicAdd(&s_neq, 1u);
      eqidx[p] = t + j * 256;
    }
  }
  __syncthreads();
  if (t == 0) {
    int base = NTOP - kneed;                   // == s_ngt
    int n = (int)s_neq;
    for (int r = 0; r < kneed; ++r) {
      int bm = 0x7fffffff, bp = 0;
      for (int i = 0; i < n; ++i)
        if (eqidx[i] < bm) { bm = eqidx[i]; bp = i; }
      top[bh * NTOP + base + r] = bm;
      eqidx[bp] = 0x7fffffff;
    }
  }
}

// ---------------- Phase 3a: partial V sums, 64 rows per block ---------------
// grid: bh*32 + chunk (1024 blocks). 16 threads cover one row (16 float4).
__global__ __launch_bounds__(256) void k_vmean1(
    const float* __restrict__ V, float* __restrict__ part)
{
  __shared__ f4 red[16][16];
  int bh = blockIdx.x >> 5, chunk = blockIdx.x & 31;
  int h = bh & 7, b = bh >> 3;
  int t = threadIdx.x;
  int d4 = t & 15, rg = t >> 4;                // rg: 0..15 row-group
  const f4* vb = (const f4*)(V + (size_t)b * L_ * HD + (size_t)h * D_);
  f4 s = {0.f, 0.f, 0.f, 0.f};
  int row0 = chunk * 64 + rg;
  #pragma unroll
  for (int r = 0; r < 4; ++r) {
    f4 v = vb[(size_t)(row0 + r * 16) * (HD / 4) + d4];
    s.x += v.x; s.y += v.y; s.z += v.z; s.w += v.w;
  }
  red[rg][d4] = s;
  __syncthreads();
  #pragma unroll
  for (int off = 8; off; off >>= 1) {
    if (rg < off) {
      f4 a = red[rg][d4], bb = red[rg + off][d4];
      a.x += bb.x; a.y += bb.y; a.z += bb.z; a.w += bb.w;
      red[rg][d4] = a;
    }
    __syncthreads();
  }
  if (rg == 0) ((f4*)part)[(size_t)blockIdx.x * 16 + d4] = red[0][d4];
}

// ---------------- Phase 3b: reduce 32 chunk partials -> vmean ---------------
__global__ __launch_bounds__(64) void k_vmean2(
    const float* __restrict__ part, float* __restrict__ vm)
{
  int bh = blockIdx.x, lane = threadIdx.x;     // lane = d
  float s = 0.f;
  #pragma unroll 8
  for (int c = 0; c < 32; ++c)
    s += part[(size_t)(bh * 32 + c) * 64 + lane];
  vm[bh * 64 + lane] = s * (1.0f / L_);
}

// ---------------- Phase 4a: fill out with Vmean broadcast --------------------
__global__ __launch_bounds__(256) void k_fill(
    const float* __restrict__ vm, float* __restrict__ out)
{
  int i = blockIdx.x * 256 + threadIdx.x;      // float4 index, 1M total
  int d4 = i & 15;
  int h  = (i >> 4) & 7;
  int b  = i >> 18;
  ((f4*)out)[i] = ((const f4*)vm)[(b * 8 + h) * 16 + d4];
}

// ---------------- Phase 4b: attention partials -------------------------------
// wave = (bh, ch of 64 keys, uq of 5 rows); lane = key for QK, lane = d for PV.
// Q rows are wave-uniform -> scalar (s_load) reads, fma sources SGPR directly.
__global__ __launch_bounds__(256) void k_attn(
    const float* __restrict__ Q, const float* __restrict__ K,
    const float* __restrict__ V, const int* __restrict__ top,
    float* __restrict__ pm, float* __restrict__ pl, float* __restrict__ pacc)
{
  int lane = threadIdx.x & 63;
  int w = __builtin_amdgcn_readfirstlane(threadIdx.x >> 6); // wave-uniform SGPR
  int gw = blockIdx.x * 4 + w;                 // ((bh*32+ch)*8 + uq)
  int uq = gw & 7;
  int ch = (gw >> 3) & 31;
  int bh = gw >> 8;
  int h = bh & 7, b = bh >> 3;
  const size_t bhoff = (size_t)b * L_ * HD + (size_t)h * D_;
  const int kbase = ch * 64;

  f4 kr[16];                                   // this lane's key row (64 f32)
  {
    const f4* krow = (const f4*)(K + bhoff + (size_t)(kbase + lane) * HD);
    #pragma unroll
    for (int j = 0; j < 16; ++j) kr[j] = krow[j];
  }
  const float* qr[5];                          // wave-uniform Q row pointers
  #pragma unroll
  for (int u = 0; u < 5; ++u) {
    int pos = __builtin_amdgcn_readfirstlane(top[bh * NTOP + uq * 5 + u]);
    qr[u] = Q + bhoff + (size_t)pos * HD;
  }
  float s[5] = {0.f, 0.f, 0.f, 0.f, 0.f};
  #pragma unroll
  for (int j = 0; j < 16; ++j) {
    f4 kv = kr[j];
    #pragma unroll
    for (int u = 0; u < 5; ++u) {
      s[u] = fmaf(qr[u][4*j+0], kv.x, s[u]);   // scalar Q load -> SGPR operand
      s[u] = fmaf(qr[u][4*j+1], kv.y, s[u]);
      s[u] = fmaf(qr[u][4*j+2], kv.z, s[u]);
      s[u] = fmaf(qr[u][4*j+3], kv.w, s[u]);
    }
  }
  float p[5];
  #pragma unroll
  for (int u = 0; u < 5; ++u) {
    float sv = s[u] * 0.125f;                  // 1/sqrt(64)
    float mx = sv;
    #pragma unroll
    for (int off = 32; off; off >>= 1) mx = fmaxf(mx, __shfl_xor(mx, off));
    float pv = __expf(sv - mx);
    float ls = pv;
    #pragma unroll
    for (int off = 32; off; off >>= 1) ls += __shfl_xor(ls, off);
    p[u] = pv;
    int e = (bh * 32 + ch) * NTOP + uq * 5 + u;
    if (lane == 0) { pm[e] = mx; pl[e] = ls; }
  }
  float acc[5] = {0.f, 0.f, 0.f, 0.f, 0.f};
  const float* vb = V + bhoff + (size_t)kbase * HD + lane;
  #pragma unroll 8
  for (int k = 0; k < 64; ++k) {
    float vv = vb[(size_t)k * HD];             // coalesced: lane = d
    #pragma unroll
    for (int u = 0; u < 5; ++u)
      acc[u] = fmaf(rl(p[u], k), vv, acc[u]);  // k literal -> readlane -> SGPR
  }
  #pragma unroll
  for (int u = 0; u < 5; ++u) {
    size_t e = (size_t)(bh * 32 + ch) * NTOP + uq * 5 + u;
    pacc[e * 64 + lane] = acc[u];
  }
}

// ---------------- Phase 5: merge partials + scatter --------------------------
__global__ __launch_bounds__(256) void k_merge(
    const float* __restrict__ pm, const float* __restrict__ pl,
    const float* __restrict__ pacc, const int* __restrict__ top,
    float* __restrict__ out)
{
  int w = threadIdx.x >> 6, lane = threadIdx.x & 63;
  int gw = blockIdx.x * 4 + w;                 // bh*40 + u, 1280 total
  int bh = gw / NTOP, u = gw - bh * NTOP;
  int h = bh & 7, b = bh >> 3;
  float M = -INFINITY, Ls = 0.f, o = 0.f;
  for (int c = 0; c < 32; ++c) {
    int e = (bh * 32 + c) * NTOP + u;
    float mc = pm[e], lc = pl[e];
    float a = pacc[(size_t)e * 64 + lane];
    float Mn = fmaxf(M, mc);
    float f1 = __expf(M - Mn), f2 = __expf(mc - Mn);
    o  = o  * f1 + a  * f2;
    Ls = Ls * f1 + lc * f2;
    M = Mn;
  }
  int pos = top[bh * NTOP + u];
  out[((size_t)(b * L_ + pos) * H_ + h) * D_ + lane] = o / Ls;
}

extern "C" void kernel_launch(void* const* d_in, const int* in_sizes, int n_in,
                              void* d_out, int out_size, void* d_ws, size_t ws_size,
                              hipStream_t stream) {
  const float* Q = (const float*)d_in[0];
  const float* K = (const float*)d_in[1];
  const float* V = (const float*)d_in[2];
  const int* samp = (const int*)d_in[3];
  float* out = (float*)d_out;

  float* ws    = (float*)d_ws;
  float* M     = ws;                       // 65536
  float* vmean = M + 65536;                // 2048
  float* pm    = vmean + 2048;             // 40960
  float* pl    = pm + 40960;               // 40960
  float* pacc  = pl + 40960;               // 2621440
  int*   top   = (int*)(pacc + 2621440);   // 1280 ints  (total ~11.1 MB)
  float* vpart = pacc;                     // alias: used only BEFORE k_attn

  hipLaunchKernelGGL(k_sampleM, dim3(2048), dim3(256), 0, stream, Q, K, samp, M);
  hipLaunchKernelGGL(k_topk,   dim3(32),   dim3(256), 0, stream, M, top);
  hipLaunchKernelGGL(k_vmean1, dim3(1024), dim3(256), 0, stream, V, vpart);
  hipLaunchKernelGGL(k_vmean2, dim3(32),   dim3(64),  0, stream, vpart, vmean);
  hipLaunchKernelGGL(k_fill,   dim3(4096), dim3(256), 0, stream, vmean, out);
  hipLaunchKernelGGL(k_attn,   dim3(2048), dim3(256), 0, stream, Q, K, V, top, pm, pl, pacc);
  hipLaunchKernelGGL(k_merge,  dim3(320),  dim3(256), 0, stream, pm, pl, pacc, top, out);
}

// Round 5
// 110.320 us; speedup vs baseline: 2.8660x; 1.2851x over previous
//
#include <hip/hip_runtime.h>
#include <math.h>

#define B_ 4
#define L_ 2048
#define H_ 8
#define D_ 64
#define SK 40
#define NTOP 40
#define HD (H_*D_)

typedef float4 f4;

// readlane: broadcast lane `l`'s value of v (uniform l) -> SGPR
static __device__ __forceinline__ float rl(float v, int l) {
  return __int_as_float(__builtin_amdgcn_readlane(__float_as_int(v), l));
}

// XCD-aware swizzle: physical block i lands on XCD i%8; give each XCD a
// contiguous range of logical ids so per-XCD L2 working set is minimized.
// Requires nblk % 8 == 0. Bijective.
static __device__ __forceinline__ int xcd_swz(int bid, int cpx) {
  return (bid & 7) * cpx + (bid >> 3);
}

// ---------------- Phase 1: M[bh,q] = max_s(Q.K_s) - sum_s(Q.K_s)/L ----------
// 8-lane groups; one query per group; 8 queries per wave; 32 per block.
__global__ __launch_bounds__(256) void k_sampleM(
    const float* __restrict__ Q, const float* __restrict__ K,
    const int* __restrict__ samp, float* __restrict__ M)
{
  int bid = xcd_swz(blockIdx.x, 256);           // 2048 blocks, 64 per bh
  int w = threadIdx.x >> 6, lane = threadIdx.x & 63;
  int g = lane >> 3, li = lane & 7;
  int gq = (bid * 4 + w) * 8 + g;               // bh*L + qpos
  int qpos = gq & (L_ - 1);
  int bh = gq >> 11;
  int h = bh & (H_ - 1), b = bh >> 3;
  const size_t bhoff = (size_t)b * L_ * HD + (size_t)h * D_;
  const f4* qrow = (const f4*)(Q + bhoff + (size_t)qpos * HD);
  f4 q0 = qrow[li], q1 = qrow[li + 8];          // contiguous 128B halves
  const int* srow = samp + qpos * SK;
  const float* kb = K + bhoff;
  float mx = -INFINITY, sm = 0.f;
  #pragma unroll 4
  for (int s = 0; s < SK; ++s) {
    int ki = srow[s];
    const f4* krow = (const f4*)(kb + (size_t)ki * HD);
    f4 k0 = krow[li], k1 = krow[li + 8];
    float p = q0.x*k0.x + q0.y*k0.y + q0.z*k0.z + q0.w*k0.w
            + q1.x*k1.x + q1.y*k1.y + q1.z*k1.z + q1.w*k1.w;
    p += __shfl_xor(p, 1);
    p += __shfl_xor(p, 2);
    p += __shfl_xor(p, 4);
    mx = fmaxf(mx, p);
    sm += p;
  }
  if (li == 0) M[gq] = mx - sm * (1.0f / L_);
}

// ---------------- Phase 2: top-40 per (b,h) via 4-pass radix select ----------
// One 256-thread block per bh. Set semantics: order in top[] is irrelevant;
// ties at the boundary take lowest indices (matches lax.top_k).
__global__ __launch_bounds__(256) void k_topk(
    const float* __restrict__ M, int* __restrict__ top)
{
  __shared__ unsigned hist[256];
  __shared__ int s_sel, s_k;
  __shared__ unsigned s_ngt, s_neq;
  __shared__ int eqidx[L_];
  int bh = blockIdx.x, t = threadIdx.x;

  unsigned v[8];                               // monotone float->uint map
  #pragma unroll
  for (int j = 0; j < 8; ++j) {
    unsigned u = __float_as_uint(M[bh * L_ + t + j * 256]);
    v[j] = (u & 0x80000000u) ? ~u : (u | 0x80000000u);
  }

  unsigned prefix = 0;
  int kneed = NTOP;
  for (int shift = 24; shift >= 0; shift -= 8) {
    hist[t] = 0;
    __syncthreads();
    unsigned msk = (shift == 24) ? 0u : (0xFFFFFFFFu << (shift + 8));
    #pragma unroll
    for (int j = 0; j < 8; ++j)
      if ((v[j] & msk) == prefix)
        atomicAdd(&hist[(v[j] >> shift) & 255u], 1u);
    __syncthreads();
    if (t == 0) {
      int kk = kneed, b = 0;
      for (b = 255; b > 0; --b) {
        int c = (int)hist[b];
        if (c >= kk) break;
        kk -= c;
      }
      s_sel = b; s_k = kk;
    }
    __syncthreads();
    prefix |= ((unsigned)s_sel) << shift;
    kneed = s_k;
  }
  // prefix == exact bit pattern of the 40th-largest value (tie-counted);
  // kneed == how many values equal to it we must take (lowest indices).
  if (t == 0) { s_ngt = 0; s_neq = 0; }
  __syncthreads();
  #pragma unroll
  for (int j = 0; j < 8; ++j) {
    if (v[j] > prefix) {
      unsigned p = atomicAdd(&s_ngt, 1u);
      top[bh * NTOP + p] = t + j * 256;
    } else if (v[j] == prefix) {
      unsigned p = atomicAdd(&s_neq, 1u);
      eqidx[p] = t + j * 256;
    }
  }
  __syncthreads();
  if (t == 0) {
    int base = NTOP - kneed;                   // == s_ngt
    int n = (int)s_neq;
    for (int r = 0; r < kneed; ++r) {
      int bm = 0x7fffffff, bp = 0;
      for (int i = 0; i < n; ++i)
        if (eqidx[i] < bm) { bm = eqidx[i]; bp = i; }
      top[bh * NTOP + base + r] = bm;
      eqidx[bp] = 0x7fffffff;
    }
  }
}

// ---------------- Phase 3a: partial V sums, 64 rows per block ---------------
// grid: bh*32 + chunk (1024 blocks). 16 threads cover one row (16 float4).
__global__ __launch_bounds__(256) void k_vmean1(
    const float* __restrict__ V, float* __restrict__ part)
{
  __shared__ f4 red[16][16];
  int bh = blockIdx.x >> 5, chunk = blockIdx.x & 31;
  int h = bh & 7, b = bh >> 3;
  int t = threadIdx.x;
  int d4 = t & 15, rg = t >> 4;                // rg: 0..15 row-group
  const f4* vb = (const f4*)(V + (size_t)b * L_ * HD + (size_t)h * D_);
  f4 s = {0.f, 0.f, 0.f, 0.f};
  int row0 = chunk * 64 + rg;
  #pragma unroll
  for (int r = 0; r < 4; ++r) {
    f4 v = vb[(size_t)(row0 + r * 16) * (HD / 4) + d4];
    s.x += v.x; s.y += v.y; s.z += v.z; s.w += v.w;
  }
  red[rg][d4] = s;
  __syncthreads();
  #pragma unroll
  for (int off = 8; off; off >>= 1) {
    if (rg < off) {
      f4 a = red[rg][d4], bb = red[rg + off][d4];
      a.x += bb.x; a.y += bb.y; a.z += bb.z; a.w += bb.w;
      red[rg][d4] = a;
    }
    __syncthreads();
  }
  if (rg == 0) ((f4*)part)[(size_t)blockIdx.x * 16 + d4] = red[0][d4];
}

// ---------------- Phase 3b: reduce 32 chunk partials -> vmean ---------------
__global__ __launch_bounds__(64) void k_vmean2(
    const float* __restrict__ part, float* __restrict__ vm)
{
  int bh = blockIdx.x, lane = threadIdx.x;     // lane = d
  float s = 0.f;
  #pragma unroll 8
  for (int c = 0; c < 32; ++c)
    s += part[(size_t)(bh * 32 + c) * 64 + lane];
  vm[bh * 64 + lane] = s * (1.0f / L_);
}

// ---------------- Phase 4a: fill out with Vmean broadcast --------------------
__global__ __launch_bounds__(256) void k_fill(
    const float* __restrict__ vm, float* __restrict__ out)
{
  int i = blockIdx.x * 256 + threadIdx.x;      // float4 index, 1M total
  int d4 = i & 15;
  int h  = (i >> 4) & 7;
  int b  = i >> 18;
  ((f4*)out)[i] = ((const f4*)vm)[(b * 8 + h) * 16 + d4];
}

// ---------------- Phase 4b: attention partials -------------------------------
// wave = (bh, ch of 64 keys, uq of 5 rows); lane = key for QK, lane = d for PV.
// Q rows are wave-uniform -> scalar (s_load) reads, fma sources SGPR directly.
__global__ __launch_bounds__(256) void k_attn(
    const float* __restrict__ Q, const float* __restrict__ K,
    const float* __restrict__ V, const int* __restrict__ top,
    float* __restrict__ pm, float* __restrict__ pl, float* __restrict__ pacc)
{
  int bid = xcd_swz(blockIdx.x, 256);          // 2048 blocks, 64 per bh
  int lane = threadIdx.x & 63;
  int w = __builtin_amdgcn_readfirstlane(threadIdx.x >> 6); // wave-uniform SGPR
  int gw = bid * 4 + w;                        // ((bh*32+ch)*8 + uq)
  int uq = gw & 7;
  int ch = (gw >> 3) & 31;
  int bh = gw >> 8;
  int h = bh & 7, b = bh >> 3;
  const size_t bhoff = (size_t)b * L_ * HD + (size_t)h * D_;
  const int kbase = ch * 64;

  f4 kr[16];                                   // this lane's key row (64 f32)
  {
    const f4* krow = (const f4*)(K + bhoff + (size_t)(kbase + lane) * HD);
    #pragma unroll
    for (int j = 0; j < 16; ++j) kr[j] = krow[j];
  }
  const float* qr[5];                          // wave-uniform Q row pointers
  #pragma unroll
  for (int u = 0; u < 5; ++u) {
    int pos = __builtin_amdgcn_readfirstlane(top[bh * NTOP + uq * 5 + u]);
    qr[u] = Q + bhoff + (size_t)pos * HD;
  }
  float s[5] = {0.f, 0.f, 0.f, 0.f, 0.f};
  #pragma unroll
  for (int j = 0; j < 16; ++j) {
    f4 kv = kr[j];
    #pragma unroll
    for (int u = 0; u < 5; ++u) {
      s[u] = fmaf(qr[u][4*j+0], kv.x, s[u]);   // scalar Q load -> SGPR operand
      s[u] = fmaf(qr[u][4*j+1], kv.y, s[u]);
      s[u] = fmaf(qr[u][4*j+2], kv.z, s[u]);
      s[u] = fmaf(qr[u][4*j+3], kv.w, s[u]);
    }
  }
  float p[5];
  #pragma unroll
  for (int u = 0; u < 5; ++u) {
    float sv = s[u] * 0.125f;                  // 1/sqrt(64)
    float mx = sv;
    #pragma unroll
    for (int off = 32; off; off >>= 1) mx = fmaxf(mx, __shfl_xor(mx, off));
    float pv = __expf(sv - mx);
    float ls = pv;
    #pragma unroll
    for (int off = 32; off; off >>= 1) ls += __shfl_xor(ls, off);
    p[u] = pv;
    int e = (bh * 32 + ch) * NTOP + uq * 5 + u;
    if (lane == 0) { pm[e] = mx; pl[e] = ls; }
  }
  float acc[5] = {0.f, 0.f, 0.f, 0.f, 0.f};
  const float* vb = V + bhoff + (size_t)kbase * HD + lane;
  #pragma unroll 8
  for (int k = 0; k < 64; ++k) {
    float vv = vb[(size_t)k * HD];             // coalesced: lane = d
    #pragma unroll
    for (int u = 0; u < 5; ++u)
      acc[u] = fmaf(rl(p[u], k), vv, acc[u]);  // k literal -> readlane -> SGPR
  }
  #pragma unroll
  for (int u = 0; u < 5; ++u) {
    size_t e = (size_t)(bh * 32 + ch) * NTOP + uq * 5 + u;
    pacc[e * 64 + lane] = acc[u];
  }
}

// ---------------- Phase 5: merge partials + scatter --------------------------
__global__ __launch_bounds__(256) void k_merge(
    const float* __restrict__ pm, const float* __restrict__ pl,
    const float* __restrict__ pacc, const int* __restrict__ top,
    float* __restrict__ out)
{
  int w = threadIdx.x >> 6, lane = threadIdx.x & 63;
  int gw = blockIdx.x * 4 + w;                 // bh*40 + u, 1280 total
  int bh = gw / NTOP, u = gw - bh * NTOP;
  int h = bh & 7, b = bh >> 3;
  float M = -INFINITY, Ls = 0.f, o = 0.f;
  for (int c = 0; c < 32; ++c) {
    int e = (bh * 32 + c) * NTOP + u;
    float mc = pm[e], lc = pl[e];
    float a = pacc[(size_t)e * 64 + lane];
    float Mn = fmaxf(M, mc);
    float f1 = __expf(M - Mn), f2 = __expf(mc - Mn);
    o  = o  * f1 + a  * f2;
    Ls = Ls * f1 + lc * f2;
    M = Mn;
  }
  int pos = top[bh * NTOP + u];
  out[((size_t)(b * L_ + pos) * H_ + h) * D_ + lane] = o / Ls;
}

extern "C" void kernel_launch(void* const* d_in, const int* in_sizes, int n_in,
                              void* d_out, int out_size, void* d_ws, size_t ws_size,
                              hipStream_t stream) {
  const float* Q = (const float*)d_in[0];
  const float* K = (const float*)d_in[1];
  const float* V = (const float*)d_in[2];
  const int* samp = (const int*)d_in[3];
  float* out = (float*)d_out;

  float* ws    = (float*)d_ws;
  float* M     = ws;                       // 65536
  float* vmean = M + 65536;                // 2048
  float* pm    = vmean + 2048;             // 40960
  float* pl    = pm + 40960;               // 40960
  float* pacc  = pl + 40960;               // 2621440
  int*   top   = (int*)(pacc + 2621440);   // 1280 ints  (total ~11.1 MB)
  float* vpart = pacc;                     // alias: used only BEFORE k_attn

  hipLaunchKernelGGL(k_sampleM, dim3(2048), dim3(256), 0, stream, Q, K, samp, M);
  hipLaunchKernelGGL(k_topk,   dim3(32),   dim3(256), 0, stream, M, top);
  hipLaunchKernelGGL(k_vmean1, dim3(1024), dim3(256), 0, stream, V, vpart);
  hipLaunchKernelGGL(k_vmean2, dim3(32),   dim3(64),  0, stream, vpart, vmean);
  hipLaunchKernelGGL(k_fill,   dim3(4096), dim3(256), 0, stream, vmean, out);
  hipLaunchKernelGGL(k_attn,   dim3(2048), dim3(256), 0, stream, Q, K, V, top, pm, pl, pacc);
  hipLaunchKernelGGL(k_merge,  dim3(320),  dim3(256), 0, stream, pm, pl, pacc, top, out);
}

// Round 6
// 84.043 us; speedup vs baseline: 3.7620x; 1.3127x over previous
//
#include <hip/hip_runtime.h>
#include <math.h>

#define B_ 4
#define L_ 2048
#define H_ 8
#define D_ 64
#define SK 40
#define NTOP 40
#define HD (H_*D_)

typedef float4 f4;

// readlane: broadcast lane `l`'s value of v (uniform l) -> SGPR
static __device__ __forceinline__ float rl(float v, int l) {
  return __int_as_float(__builtin_amdgcn_readlane(__float_as_int(v), l));
}

// XCD-aware swizzle: physical block i lands on XCD i%8; give each XCD a
// contiguous range of logical ids so per-XCD L2 working set is minimized.
// Requires nblk % 8 == 0. Bijective.
static __device__ __forceinline__ int xcd_swz(int bid, int cpx) {
  return (bid & 7) * cpx + (bid >> 3);
}

// ---------------- Phase 1: M[bh,q] = max_s(Q.K_s) - sum_s(Q.K_s)/L ----------
// 8-lane groups; one query per group; 8 queries per wave; 32 per block.
__global__ __launch_bounds__(256) void k_sampleM(
    const float* __restrict__ Q, const float* __restrict__ K,
    const int* __restrict__ samp, float* __restrict__ M)
{
  int bid = xcd_swz(blockIdx.x, 256);           // 2048 blocks, 64 per bh
  int w = threadIdx.x >> 6, lane = threadIdx.x & 63;
  int g = lane >> 3, li = lane & 7;
  int gq = (bid * 4 + w) * 8 + g;               // bh*L + qpos
  int qpos = gq & (L_ - 1);
  int bh = gq >> 11;
  int h = bh & (H_ - 1), b = bh >> 3;
  const size_t bhoff = (size_t)b * L_ * HD + (size_t)h * D_;
  const f4* qrow = (const f4*)(Q + bhoff + (size_t)qpos * HD);
  f4 q0 = qrow[li], q1 = qrow[li + 8];          // contiguous 128B halves
  const int* srow = samp + qpos * SK;
  const float* kb = K + bhoff;
  float mx = -INFINITY, sm = 0.f;
  #pragma unroll 4
  for (int s = 0; s < SK; ++s) {
    int ki = srow[s];
    const f4* krow = (const f4*)(kb + (size_t)ki * HD);
    f4 k0 = krow[li], k1 = krow[li + 8];
    float p = q0.x*k0.x + q0.y*k0.y + q0.z*k0.z + q0.w*k0.w
            + q1.x*k1.x + q1.y*k1.y + q1.z*k1.z + q1.w*k1.w;
    p += __shfl_xor(p, 1);
    p += __shfl_xor(p, 2);
    p += __shfl_xor(p, 4);
    mx = fmaxf(mx, p);
    sm += p;
  }
  if (li == 0) M[gq] = mx - sm * (1.0f / L_);
}

// ---------------- Phase 2: top-40 per (b,h) via 4-pass radix select ----------
// One 256-thread block per bh. Parallel suffix-scan bin select (no serial
// walk). Set semantics: order in top[] is irrelevant; ties at the boundary
// take lowest indices (matches lax.top_k).
__global__ __launch_bounds__(256) void k_topk(
    const float* __restrict__ M, int* __restrict__ top)
{
  __shared__ unsigned hist[256];
  __shared__ unsigned sfx[256];
  __shared__ int s_sel, s_k;
  __shared__ unsigned s_ngt, s_neq;
  __shared__ int eqidx[L_];
  int bh = blockIdx.x, t = threadIdx.x;

  unsigned v[8];                               // monotone float->uint map
  #pragma unroll
  for (int j = 0; j < 8; ++j) {
    unsigned u = __float_as_uint(M[bh * L_ + t + j * 256]);
    v[j] = (u & 0x80000000u) ? ~u : (u | 0x80000000u);
  }

  unsigned prefix = 0;
  int kneed = NTOP;
  for (int shift = 24; shift >= 0; shift -= 8) {
    hist[t] = 0;
    __syncthreads();
    unsigned msk = (shift == 24) ? 0u : (0xFFFFFFFFu << (shift + 8));
    #pragma unroll
    for (int j = 0; j < 8; ++j)
      if ((v[j] & msk) == prefix)
        atomicAdd(&hist[(v[j] >> shift) & 255u], 1u);
    __syncthreads();
    // parallel inclusive suffix sum: sfx[t] = sum_{j>=t} hist[j]
    sfx[t] = hist[t];
    __syncthreads();
    #pragma unroll
    for (int off = 1; off < 256; off <<= 1) {
      unsigned add = (t + off < 256) ? sfx[t + off] : 0u;
      __syncthreads();
      sfx[t] += add;
      __syncthreads();
    }
    unsigned Sm = sfx[t];
    unsigned Sn = (t < 255) ? sfx[t + 1] : 0u;
    if (Sm >= (unsigned)kneed && Sn < (unsigned)kneed) {
      s_sel = t;                               // unique thread
      s_k = kneed - (int)Sn;
    }
    __syncthreads();
    prefix |= ((unsigned)s_sel) << shift;
    kneed = s_k;
  }
  // prefix == exact bit pattern of the 40th-largest value (tie-counted);
  // kneed == how many values equal to it we must take (lowest indices).
  if (t == 0) { s_ngt = 0; s_neq = 0; }
  __syncthreads();
  #pragma unroll
  for (int j = 0; j < 8; ++j) {
    if (v[j] > prefix) {
      unsigned p = atomicAdd(&s_ngt, 1u);
      top[bh * NTOP + p] = t + j * 256;
    } else if (v[j] == prefix) {
      unsigned p = atomicAdd(&s_neq, 1u);
      eqidx[p] = t + j * 256;
    }
  }
  __syncthreads();
  if (t == 0) {
    int base = NTOP - kneed;                   // == s_ngt
    int n = (int)s_neq;                        // usually 1
    for (int r = 0; r < kneed; ++r) {
      int bm = 0x7fffffff, bp = 0;
      for (int i = 0; i < n; ++i)
        if (eqidx[i] < bm) { bm = eqidx[i]; bp = i; }
      top[bh * NTOP + base + r] = bm;
      eqidx[bp] = 0x7fffffff;
    }
  }
}

// ---------------- Phase 3a: partial V sums, 64 rows per block ---------------
// grid: bh*32 + chunk (1024 blocks). 16 threads cover one row (16 float4).
__global__ __launch_bounds__(256) void k_vmean1(
    const float* __restrict__ V, float* __restrict__ part)
{
  __shared__ f4 red[16][16];
  int bh = blockIdx.x >> 5, chunk = blockIdx.x & 31;
  int h = bh & 7, b = bh >> 3;
  int t = threadIdx.x;
  int d4 = t & 15, rg = t >> 4;                // rg: 0..15 row-group
  const f4* vb = (const f4*)(V + (size_t)b * L_ * HD + (size_t)h * D_);
  f4 s = {0.f, 0.f, 0.f, 0.f};
  int row0 = chunk * 64 + rg;
  #pragma unroll
  for (int r = 0; r < 4; ++r) {
    f4 v = vb[(size_t)(row0 + r * 16) * (HD / 4) + d4];
    s.x += v.x; s.y += v.y; s.z += v.z; s.w += v.w;
  }
  red[rg][d4] = s;
  __syncthreads();
  #pragma unroll
  for (int off = 8; off; off >>= 1) {
    if (rg < off) {
      f4 a = red[rg][d4], bb = red[rg + off][d4];
      a.x += bb.x; a.y += bb.y; a.z += bb.z; a.w += bb.w;
      red[rg][d4] = a;
    }
    __syncthreads();
  }
  if (rg == 0) ((f4*)part)[(size_t)blockIdx.x * 16 + d4] = red[0][d4];
}

// ---------------- Phase 3b: reduce 32 chunk partials -> vmean ---------------
__global__ __launch_bounds__(64) void k_vmean2(
    const float* __restrict__ part, float* __restrict__ vm)
{
  int bh = blockIdx.x, lane = threadIdx.x;     // lane = d
  float s = 0.f;
  #pragma unroll 8
  for (int c = 0; c < 32; ++c)
    s += part[(size_t)(bh * 32 + c) * 64 + lane];
  vm[bh * 64 + lane] = s * (1.0f / L_);
}

// ---------------- Phase 4a: fill out with Vmean broadcast --------------------
__global__ __launch_bounds__(256) void k_fill(
    const float* __restrict__ vm, float* __restrict__ out)
{
  int i = blockIdx.x * 256 + threadIdx.x;      // float4 index, 1M total
  int d4 = i & 15;
  int h  = (i >> 4) & 7;
  int b  = i >> 18;
  ((f4*)out)[i] = ((const f4*)vm)[(b * 8 + h) * 16 + d4];
}

// ---------------- Phase 4b: attention partials -------------------------------
// wave = (bh, ch of 64 keys, uq of 5 rows); lane = key for QK, lane = d for PV.
// Q rows wave-uniform -> scalar loads. PV: P broadcast via LDS ds_read_b128.
__global__ __launch_bounds__(256) void k_attn(
    const float* __restrict__ Q, const float* __restrict__ K,
    const float* __restrict__ V, const int* __restrict__ top,
    float* __restrict__ pm, float* __restrict__ pl, float* __restrict__ pacc)
{
  __shared__ float plds[4][5][64];
  int bid = xcd_swz(blockIdx.x, 256);          // 2048 blocks, 64 per bh
  int lane = threadIdx.x & 63;
  int w = __builtin_amdgcn_readfirstlane(threadIdx.x >> 6); // wave-uniform SGPR
  int gw = bid * 4 + w;                        // ((bh*32+ch)*8 + uq)
  int uq = gw & 7;
  int ch = (gw >> 3) & 31;
  int bh = gw >> 8;
  int h = bh & 7, b = bh >> 3;
  const size_t bhoff = (size_t)b * L_ * HD + (size_t)h * D_;
  const int kbase = ch * 64;

  f4 kr[16];                                   // this lane's key row (64 f32)
  {
    const f4* krow = (const f4*)(K + bhoff + (size_t)(kbase + lane) * HD);
    #pragma unroll
    for (int j = 0; j < 16; ++j) kr[j] = krow[j];
  }
  const float* qr[5];                          // wave-uniform Q row pointers
  #pragma unroll
  for (int u = 0; u < 5; ++u) {
    int pos = __builtin_amdgcn_readfirstlane(top[bh * NTOP + uq * 5 + u]);
    qr[u] = Q + bhoff + (size_t)pos * HD;
  }
  float s[5] = {0.f, 0.f, 0.f, 0.f, 0.f};
  #pragma unroll
  for (int j = 0; j < 16; ++j) {
    f4 kv = kr[j];
    #pragma unroll
    for (int u = 0; u < 5; ++u) {
      s[u] = fmaf(qr[u][4*j+0], kv.x, s[u]);   // scalar Q load -> SGPR operand
      s[u] = fmaf(qr[u][4*j+1], kv.y, s[u]);
      s[u] = fmaf(qr[u][4*j+2], kv.z, s[u]);
      s[u] = fmaf(qr[u][4*j+3], kv.w, s[u]);
    }
  }
  #pragma unroll
  for (int u = 0; u < 5; ++u) {
    float sv = s[u] * 0.125f;                  // 1/sqrt(64)
    float mx = sv;
    #pragma unroll
    for (int off = 32; off; off >>= 1) mx = fmaxf(mx, __shfl_xor(mx, off));
    float pv = __expf(sv - mx);
    float ls = pv;
    #pragma unroll
    for (int off = 32; off; off >>= 1) ls += __shfl_xor(ls, off);
    plds[w][u][lane] = pv;                     // P-row to LDS (lane = key)
    int e = (bh * 32 + ch) * NTOP + uq * 5 + u;
    if (lane == 0) { pm[e] = mx; pl[e] = ls; }
  }
  __syncthreads();                             // plds visible (uniform flow)
  float acc[5] = {0.f, 0.f, 0.f, 0.f, 0.f};
  const float* vb = V + bhoff + (size_t)kbase * HD + lane;
  const f4* pw = (const f4*)&plds[w][0][0];    // [5][16] float4 view
  #pragma unroll
  for (int j = 0; j < 16; ++j) {               // 4 keys per step
    float vv0 = vb[(size_t)(4*j+0) * HD];      // coalesced: lane = d
    float vv1 = vb[(size_t)(4*j+1) * HD];
    float vv2 = vb[(size_t)(4*j+2) * HD];
    float vv3 = vb[(size_t)(4*j+3) * HD];
    f4 pj[5];
    #pragma unroll
    for (int u = 0; u < 5; ++u) pj[u] = pw[u * 16 + j];  // LDS broadcast
    #pragma unroll
    for (int u = 0; u < 5; ++u) {
      acc[u] = fmaf(pj[u].x, vv0, acc[u]);
      acc[u] = fmaf(pj[u].y, vv1, acc[u]);
      acc[u] = fmaf(pj[u].z, vv2, acc[u]);
      acc[u] = fmaf(pj[u].w, vv3, acc[u]);
    }
  }
  #pragma unroll
  for (int u = 0; u < 5; ++u) {
    size_t e = (size_t)(bh * 32 + ch) * NTOP + uq * 5 + u;
    pacc[e * 64 + lane] = acc[u];
  }
}

// ---------------- Phase 5: merge partials + scatter --------------------------
// Parallel: lanes 0..31 hold one chunk's (m,l) each; wave-reduce global max,
// precompute factors, then 32 independent pipelined pacc loads.
__global__ __launch_bounds__(256) void k_merge(
    const float* __restrict__ pm, const float* __restrict__ pl,
    const float* __restrict__ pacc, const int* __restrict__ top,
    float* __restrict__ out)
{
  int w = threadIdx.x >> 6, lane = threadIdx.x & 63;
  int gw = blockIdx.x * 4 + w;                 // bh*40 + u, 1280 total
  int bh = gw / NTOP, u = gw - bh * NTOP;
  int h = bh & 7, b = bh >> 3;
  int c = lane & 31;
  int e = (bh * 32 + c) * NTOP + u;
  float mc = pm[e], lc = pl[e];                // upper half: duplicate loads
  if (lane >= 32) { mc = -INFINITY; lc = 0.f; }
  float Mg = mc;
  #pragma unroll
  for (int off = 32; off; off >>= 1) Mg = fmaxf(Mg, __shfl_xor(Mg, off));
  float fc = __expf(mc - Mg);                  // 0 for upper half
  float fl = fc * lc;
  float Lg = fl;
  #pragma unroll
  for (int off = 32; off; off >>= 1) Lg += __shfl_xor(Lg, off);
  float o = 0.f;
  const float* pa = pacc + ((size_t)(bh * 32) * NTOP + u) * 64 + lane;
  #pragma unroll
  for (int cc = 0; cc < 32; ++cc)              // independent loads, pipelined
    o = fmaf(rl(fc, cc), pa[(size_t)cc * NTOP * 64], o);
  int pos = top[bh * NTOP + u];
  out[((size_t)(b * L_ + pos) * H_ + h) * D_ + lane] = o / Lg;
}

extern "C" void kernel_launch(void* const* d_in, const int* in_sizes, int n_in,
                              void* d_out, int out_size, void* d_ws, size_t ws_size,
                              hipStream_t stream) {
  const float* Q = (const float*)d_in[0];
  const float* K = (const float*)d_in[1];
  const float* V = (const float*)d_in[2];
  const int* samp = (const int*)d_in[3];
  float* out = (float*)d_out;

  float* ws    = (float*)d_ws;
  float* M     = ws;                       // 65536
  float* vmean = M + 65536;                // 2048
  float* pm    = vmean + 2048;             // 40960
  float* pl    = pm + 40960;               // 40960
  float* pacc  = pl + 40960;               // 2621440
  int*   top   = (int*)(pacc + 2621440);   // 1280 ints  (total ~11.1 MB)
  float* vpart = pacc;                     // alias: used only BEFORE k_attn

  hipLaunchKernelGGL(k_sampleM, dim3(2048), dim3(256), 0, stream, Q, K, samp, M);
  hipLaunchKernelGGL(k_topk,   dim3(32),   dim3(256), 0, stream, M, top);
  hipLaunchKernelGGL(k_vmean1, dim3(1024), dim3(256), 0, stream, V, vpart);
  hipLaunchKernelGGL(k_vmean2, dim3(32),   dim3(64),  0, stream, vpart, vmean);
  hipLaunchKernelGGL(k_fill,   dim3(4096), dim3(256), 0, stream, vmean, out);
  hipLaunchKernelGGL(k_attn,   dim3(2048), dim3(256), 0, stream, Q, K, V, top, pm, pl, pacc);
  hipLaunchKernelGGL(k_merge,  dim3(320),  dim3(256), 0, stream, pm, pl, pacc, top, out);
}